// Round 8
// baseline (590.841 us; speedup 1.0000x reference)
//
#include <hip/hip_runtime.h>
#include <hip/hip_fp16.h>

#define N_NODES 50000
#define N_EDGES 1600000
#define H 64
#define IN_CH 7
#define EDIM 4
#define G_GRAPHS 256
#define FC 128
#define NC 2
#define SLOPE 0.2f
#define SCAN_BLOCKS ((N_NODES + 255) / 256)   // 196

// ---------------- DPP wave-64 reductions ----------------
__device__ __forceinline__ float wave_sum_to63(float x) {
    x += __int_as_float(__builtin_amdgcn_update_dpp(0, __float_as_int(x), 0x111, 0xf, 0xf, true)); // row_shr:1
    x += __int_as_float(__builtin_amdgcn_update_dpp(0, __float_as_int(x), 0x112, 0xf, 0xf, true)); // row_shr:2
    x += __int_as_float(__builtin_amdgcn_update_dpp(0, __float_as_int(x), 0x114, 0xf, 0xf, true)); // row_shr:4
    x += __int_as_float(__builtin_amdgcn_update_dpp(0, __float_as_int(x), 0x118, 0xf, 0xf, true)); // row_shr:8
    x += __int_as_float(__builtin_amdgcn_update_dpp(0, __float_as_int(x), 0x142, 0xf, 0xf, true)); // row_bcast:15
    x += __int_as_float(__builtin_amdgcn_update_dpp(0, __float_as_int(x), 0x143, 0xf, 0xf, true)); // row_bcast:31
    return x;
}
// 5-step: lane31 = sum(lanes 0..31), lane63 = sum(lanes 32..63)
__device__ __forceinline__ float wave_sum_half(float x) {
    x += __int_as_float(__builtin_amdgcn_update_dpp(0, __float_as_int(x), 0x111, 0xf, 0xf, true));
    x += __int_as_float(__builtin_amdgcn_update_dpp(0, __float_as_int(x), 0x112, 0xf, 0xf, true));
    x += __int_as_float(__builtin_amdgcn_update_dpp(0, __float_as_int(x), 0x114, 0xf, 0xf, true));
    x += __int_as_float(__builtin_amdgcn_update_dpp(0, __float_as_int(x), 0x118, 0xf, 0xf, true));
    x += __int_as_float(__builtin_amdgcn_update_dpp(0, __float_as_int(x), 0x142, 0xf, 0xf, true)); // row_bcast:15
    return x;
}
__device__ __forceinline__ float wave_max_to63(float x) {
    int xi = __float_as_int(x);
    x = fmaxf(x, __int_as_float(__builtin_amdgcn_update_dpp(xi, xi, 0x111, 0xf, 0xf, false))); xi = __float_as_int(x);
    x = fmaxf(x, __int_as_float(__builtin_amdgcn_update_dpp(xi, xi, 0x112, 0xf, 0xf, false))); xi = __float_as_int(x);
    x = fmaxf(x, __int_as_float(__builtin_amdgcn_update_dpp(xi, xi, 0x114, 0xf, 0xf, false))); xi = __float_as_int(x);
    x = fmaxf(x, __int_as_float(__builtin_amdgcn_update_dpp(xi, xi, 0x118, 0xf, 0xf, false))); xi = __float_as_int(x);
    x = fmaxf(x, __int_as_float(__builtin_amdgcn_update_dpp(xi, xi, 0x142, 0xf, 0xf, false))); xi = __float_as_int(x);
    x = fmaxf(x, __int_as_float(__builtin_amdgcn_update_dpp(xi, xi, 0x143, 0xf, 0xf, false)));
    return x;
}
__device__ __forceinline__ float lane63_bcast(float x) {
    return __int_as_float(__builtin_amdgcn_readlane(__float_as_int(x), 63));
}
__device__ __forceinline__ float readlane_f(float x, int i) {
    return __int_as_float(__builtin_amdgcn_readlane(__float_as_int(x), i));
}

// ---------------- CSR build ----------------
__global__ void rank_kernel(const int* __restrict__ dst, int* __restrict__ deg,
                            int* __restrict__ rank) {
    int e = blockIdx.x * blockDim.x + threadIdx.x;
    if (e >= N_EDGES) return;
    rank[e] = atomicAdd(&deg[dst[e]], 1);
}

__global__ void scan_part_kernel(const int* __restrict__ deg, int* __restrict__ bsum) {
    __shared__ int lds[256];
    int b = blockIdx.x, t = threadIdx.x;
    int idx = b * 256 + t;
    lds[t] = (idx < N_NODES) ? deg[idx] : 0;
    __syncthreads();
    for (int off = 128; off >= 1; off >>= 1) {
        if (t < off) lds[t] += lds[t + off];
        __syncthreads();
    }
    if (t == 0) bsum[b] = lds[0];
}

__global__ void scan_top_kernel(const int* __restrict__ bsum, int* __restrict__ boff) {
    __shared__ int lds[256];
    int t = threadIdx.x;
    int v = (t < SCAN_BLOCKS) ? bsum[t] : 0;
    lds[t] = v;
    __syncthreads();
    for (int off = 1; off < 256; off <<= 1) {
        int x = (t >= off) ? lds[t - off] : 0;
        __syncthreads();
        lds[t] += x;
        __syncthreads();
    }
    boff[t] = lds[t] - v;   // exclusive
}

__global__ void scan_final_kernel(const int* __restrict__ deg, const int* __restrict__ boff,
                                  int* __restrict__ row_start) {
    __shared__ int lds[256];
    int b = blockIdx.x, t = threadIdx.x;
    int idx = b * 256 + t;
    int v = (idx < N_NODES) ? deg[idx] : 0;
    lds[t] = v;
    __syncthreads();
    for (int off = 1; off < 256; off <<= 1) {
        int x = (t >= off) ? lds[t - off] : 0;
        __syncthreads();
        lds[t] += x;
        __syncthreads();
    }
    int excl = boff[b] + lds[t] - v;
    if (idx < N_NODES) {
        row_start[idx] = excl;
        if (idx == N_NODES - 1) row_start[N_NODES] = excl + v;
    }
}

// scatter packed 16B entries {src, fp16x2(ea01), fp16x2(ea23), 0}
__global__ void scatter_kernel(const int* __restrict__ src, const int* __restrict__ dst,
                               const int* __restrict__ rank, const int* __restrict__ row_start,
                               const float* __restrict__ edge_attr,
                               int4* __restrict__ csr) {
    int e = blockIdx.x * blockDim.x + threadIdx.x;
    if (e >= N_EDGES) return;
    int d = dst[e];
    int slot = row_start[d] + rank[e];
    float4 ea = ((const float4*)edge_attr)[e];
    __half2 h01 = __floats2half2_rn(ea.x, ea.y);
    __half2 h23 = __floats2half2_rn(ea.z, ea.w);
    int4 ent;
    ent.x = src[e];
    ent.y = *reinterpret_cast<int*>(&h01);
    ent.z = *reinterpret_cast<int*>(&h23);
    ent.w = 0;
    csr[slot] = ent;
}

// ---------------- node projection -> packed fp16 channel pairs ----------------
// Thread idx covers (node, channel-pair). Writes __half2 per 2 channels.
template <int K>
__global__ void proj_kernel(const float* __restrict__ xin,
                            const float* __restrict__ Wl, const float* __restrict__ bl,
                            const float* __restrict__ Wr, const float* __restrict__ br,
                            __half2* __restrict__ xlh, __half2* __restrict__ xrh) {
    int idx = blockIdx.x * blockDim.x + threadIdx.x;
    if (idx >= N_NODES * 32) return;
    int n = idx >> 5;
    int c = idx & 31;
    const float* xi = xin + n * K;
    float2 bl2 = ((const float2*)bl)[c];
    float2 br2 = ((const float2*)br)[c];
    float al0 = bl2.x, al1 = bl2.y, ar0 = br2.x, ar1 = br2.y;
#pragma unroll
    for (int k = 0; k < K; ++k) {
        float xv = xi[k];
        float2 wl2 = ((const float2*)(Wl + k * H))[c];
        float2 wr2 = ((const float2*)(Wr + k * H))[c];
        al0 += xv * wl2.x; al1 += xv * wl2.y;
        ar0 += xv * wr2.x; ar1 += xv * wr2.y;
    }
    xlh[idx] = __floats2half2_rn(al0, al1);
    xrh[idx] = __floats2half2_rn(ar0, ar1);
}

// ---------------- fused GAT aggregation: one wave per dst node ----------------
// Half-wave layout: lanes 0..31 = edge A, lanes 32..63 = edge B; each lane owns
// a channel PAIR (fp16x2). Chunk = 32 edges (16 pairs, fully unrolled); loaded
// xl2 values stay in registers so phase 2 does zero memory traffic.
__global__ __launch_bounds__(256) void gat_gather_kernel(
        const int* __restrict__ row_start,
        const int4* __restrict__ csr,
        const __half2* __restrict__ xlh, const __half2* __restrict__ xrh,
        const float* __restrict__ We, const float* __restrict__ att,
        const float* __restrict__ bias,
        float* __restrict__ out) {
    int wave = (blockIdx.x * blockDim.x + threadIdx.x) >> 6;
    if (wave >= N_NODES) return;
    int lane = threadIdx.x & 63;
    int c = lane & 31;        // channel pair (2c, 2c+1)
    int hb = lane >> 5;       // 0: edge A, 1: edge B
    int d = wave;
    __half2 xr2 = xrh[d * 32 + c];
    float2 att2 = ((const float2*)att)[c];
    float2 w0f = ((const float2*)(We + 0 * H))[c];
    float2 w1f = ((const float2*)(We + 1 * H))[c];
    float2 w2f = ((const float2*)(We + 2 * H))[c];
    float2 w3f = ((const float2*)(We + 3 * H))[c];
    __half2 we0 = __floats2half2_rn(w0f.x, w0f.y);
    __half2 we1 = __floats2half2_rn(w1f.x, w1f.y);
    __half2 we2 = __floats2half2_rn(w2f.x, w2f.y);
    __half2 we3 = __floats2half2_rn(w3f.x, w3f.y);
    int beg = __builtin_amdgcn_readfirstlane(row_start[d]);
    int end = __builtin_amdgcn_readfirstlane(row_start[d + 1]);

    float m_run = -INFINITY, l_run = 0.f;
    float accx = 0.f, accy = 0.f;

    for (int cbeg = beg; cbeg < end; cbeg += 32) {
        int n = min(32, end - cbeg);
        __half2 xs[16];
        float scv = -INFINITY;

        // ---- phase 0: 16 pairs, branch-free (tail garbage gets p=0) ----
#pragma unroll
        for (int t = 0; t < 16; ++t) {
            int j0 = 2 * t, j1 = 2 * t + 1;
            int idx = cbeg + j0 + hb;
            idx = min(idx, end - 1);            // clamp tail (dup last edge)
            int4 ent = csr[idx];
            __half2 xl2 = xlh[ent.x * 32 + c];
            xs[t] = xl2;
            __half2 ea01 = *reinterpret_cast<__half2*>(&ent.y);
            __half2 ea23 = *reinterpret_cast<__half2*>(&ent.z);
            __half2 v2 = __hadd2(xl2, xr2);
            v2 = __hfma2(__low2half2(ea01),  we0, v2);
            v2 = __hfma2(__high2half2(ea01), we1, v2);
            v2 = __hfma2(__low2half2(ea23),  we2, v2);
            v2 = __hfma2(__high2half2(ea23), we3, v2);
            float2 vf = __half22float2(v2);
            float L0 = fmaxf(vf.x, SLOPE * vf.x);
            float L1 = fmaxf(vf.y, SLOPE * vf.y);
            float r = L0 * att2.x + L1 * att2.y;
            r = wave_sum_half(r);               // lane31 = edge A, lane63 = edge B
            float rA = readlane_f(r, 31);
            float rB = readlane_f(r, 63);
            if (j0 < n) scv = (lane == j0) ? rA : scv;
            if (j1 < n) scv = (lane == j1) ? rB : scv;
        }

        // ---- phase 1: chunk softmax ----
        float m_chunk = lane63_bcast(wave_max_to63(scv));
        float m_new = fmaxf(m_run, m_chunk);
        float corr = __expf(m_run - m_new);     // first chunk: exp(-inf)=0
        float p = __expf(scv - m_new);          // undeposited lanes: p=0
        float psum = lane63_bcast(wave_sum_to63(p));
        l_run = l_run * corr + psum;
        accx *= corr; accy *= corr;
        m_run = m_new;

        // ---- phase 2: weighted accumulation from registers (no memory) ----
#pragma unroll
        for (int t = 0; t < 16; ++t) {
            float pA = readlane_f(p, 2 * t);
            float pB = readlane_f(p, 2 * t + 1);
            float pv = hb ? pB : pA;
            float2 xf = __half22float2(xs[t]);
            accx += pv * xf.x;
            accy += pv * xf.y;
        }
    }

    // combine halves (A-lanes + B-lanes hold same channels)
    accx += __shfl_xor(accx, 32, 64);
    accy += __shfl_xor(accy, 32, 64);
    if (hb == 0) {
        float inv = 1.f / (l_run + 1e-16f);
        float2 b2 = ((const float2*)bias)[c];
        float o0 = accx * inv + b2.x;
        float o1 = accy * inv + b2.y;
        o0 = o0 > 0.f ? o0 : expm1f(o0);
        o1 = o1 > 0.f ? o1 : expm1f(o1);
        ((float2*)out)[d * 32 + c] = float2{o0, o1};
    }
}

// ---------------- pool: one block per graph, binary search on sorted batch ----------------
__global__ __launch_bounds__(256) void pool_mean_kernel(const float* __restrict__ h,
                                                        const int* __restrict__ batch,
                                                        float* __restrict__ gmean) {
    int g = blockIdx.x;
    int lo = 0, hi = N_NODES;
    while (lo < hi) { int mid = (lo + hi) >> 1; if (batch[mid] < g) lo = mid + 1; else hi = mid; }
    int start = lo;
    hi = N_NODES;
    while (lo < hi) { int mid = (lo + hi) >> 1; if (batch[mid] < g + 1) lo = mid + 1; else hi = mid; }
    int end = lo;

    int lane = threadIdx.x & 63;
    int w = threadIdx.x >> 6;
    float s = 0.f;
    for (int n = start + w; n < end; n += 4) s += h[n * H + lane];
    __shared__ float red[4][H];
    red[w][lane] = s;
    __syncthreads();
    if (w == 0) {
        float tot = red[0][lane] + red[1][lane] + red[2][lane] + red[3][lane];
        float cn = (float)(end - start);
        gmean[g * H + lane] = tot / fmaxf(cn, 1.f);
    }
}

// ---------------- head ----------------
__global__ void head_kernel(const float* __restrict__ gmean,
                            const float* __restrict__ fc1w, const float* __restrict__ fc1b,
                            const float* __restrict__ fc2w, const float* __restrict__ fc2b,
                            float* __restrict__ out) {
    __shared__ float g[H];
    __shared__ float f[FC];
    __shared__ float lg[NC];
    int b = blockIdx.x, t = threadIdx.x;
    if (t < H) g[t] = gmean[b * H + t];
    __syncthreads();
    float acc = fc1b[t];
    for (int k = 0; k < H; ++k) acc += g[k] * fc1w[k * FC + t];
    f[t] = fmaxf(acc, 0.f);
    __syncthreads();
    if (t < NC) {
        float a = fc2b[t];
        for (int k = 0; k < FC; ++k) a += f[k] * fc2w[k * NC + t];
        lg[t] = a;
    }
    __syncthreads();
    if (t < NC) {
        float mx = fmaxf(lg[0], lg[1]);
        float lse = mx + logf(expf(lg[0] - mx) + expf(lg[1] - mx));
        out[b * NC + t] = lg[t] - lse;
    }
}

extern "C" void kernel_launch(void* const* d_in, const int* in_sizes, int n_in,
                              void* d_out, int out_size, void* d_ws, size_t ws_size,
                              hipStream_t stream) {
    const float* x         = (const float*)d_in[0];
    const int*   edge_idx  = (const int*)d_in[1];
    const float* edge_attr = (const float*)d_in[2];
    const int*   batch     = (const int*)d_in[3];
    const float* Wl0  = (const float*)d_in[4];
    const float* bl0  = (const float*)d_in[5];
    const float* Wr0  = (const float*)d_in[6];
    const float* br0  = (const float*)d_in[7];
    const float* We0  = (const float*)d_in[8];
    const float* att0 = (const float*)d_in[9];
    const float* bias0= (const float*)d_in[10];
    const float* Wl1  = (const float*)d_in[11];
    const float* bl1  = (const float*)d_in[12];
    const float* Wr1  = (const float*)d_in[13];
    const float* br1  = (const float*)d_in[14];
    const float* We1  = (const float*)d_in[15];
    const float* att1 = (const float*)d_in[16];
    const float* bias1= (const float*)d_in[17];
    const float* fc1w = (const float*)d_in[18];
    const float* fc1b = (const float*)d_in[19];
    const float* fc2w = (const float*)d_in[20];
    const float* fc2b = (const float*)d_in[21];

    const int NH = N_NODES * H;
    __half2* xlh    = (__half2*)d_ws;                 // [N*32]
    __half2* xrh    = xlh + N_NODES * 32;             // [N*32]
    float* C        = (float*)(xrh + N_NODES * 32);   // layer output [N,H] fp32
    int*   deg      = (int*)(C + NH);                 // [N]
    int*   row_start= deg + N_NODES;                  // [N+1]
    int*   bsum     = row_start + N_NODES + 1;        // [256]
    int*   boff     = bsum + 256;                     // [256]
    char*  after    = (char*)(boff + 256);
    size_t csr_off  = (((size_t)(after - (char*)d_ws)) + 15) & ~(size_t)15;
    int4*  csr      = (int4*)((char*)d_ws + csr_off); // [E] packed 16B
    float* gmean    = (float*)((char*)csr + (size_t)N_EDGES * sizeof(int4)); // [G,H]
    int*   rank     = (int*)(gmean + G_GRAPHS * H);   // [E]

    const int* src = edge_idx;
    const int* dst = edge_idx + N_EDGES;

    const int pairBlocks = (N_NODES * 32 + 255) / 256;
    const int nodeBlocks = (NH + 255) / 256;
    const int edgeBlocks = (N_EDGES + 255) / 256;
    const int waveBlocks = (N_NODES * 64 + 255) / 256;

    // ---- CSR build ----
    (void)hipMemsetAsync(deg, 0, (size_t)N_NODES * sizeof(int), stream);
    rank_kernel<<<edgeBlocks, 256, 0, stream>>>(dst, deg, rank);
    scan_part_kernel<<<SCAN_BLOCKS, 256, 0, stream>>>(deg, bsum);
    scan_top_kernel<<<1, 256, 0, stream>>>(bsum, boff);
    scan_final_kernel<<<SCAN_BLOCKS, 256, 0, stream>>>(deg, boff, row_start);
    scatter_kernel<<<edgeBlocks, 256, 0, stream>>>(src, dst, rank, row_start, edge_attr, csr);

    // ---- layer 0 ----
    proj_kernel<IN_CH><<<pairBlocks, 256, 0, stream>>>(x, Wl0, bl0, Wr0, br0, xlh, xrh);
    gat_gather_kernel<<<waveBlocks, 256, 0, stream>>>(row_start, csr, xlh, xrh, We0, att0, bias0, C);

    // ---- layer 1 ----
    proj_kernel<H><<<pairBlocks, 256, 0, stream>>>(C, Wl1, bl1, Wr1, br1, xlh, xrh);
    gat_gather_kernel<<<waveBlocks, 256, 0, stream>>>(row_start, csr, xlh, xrh, We1, att1, bias1, C);

    // ---- pool + head ----
    pool_mean_kernel<<<G_GRAPHS, 256, 0, stream>>>(C, batch, gmean);
    head_kernel<<<G_GRAPHS, FC, 0, stream>>>(gmean, fc1w, fc1b, fc2w, fc2b, (float*)d_out);
}

// Round 10
// 571.591 us; speedup vs baseline: 1.0337x; 1.0337x over previous
//
#include <hip/hip_runtime.h>
#include <hip/hip_fp16.h>

#define N_NODES 50000
#define N_EDGES 1600000
#define H 64
#define IN_CH 7
#define EDIM 4
#define G_GRAPHS 256
#define FC 128
#define NC 2
#define SLOPE 0.2f
#define SCAN_BLOCKS ((N_NODES + 255) / 256)   // 196

// ---------------- DPP wave-64 reductions ----------------
__device__ __forceinline__ float wave_sum_to63(float x) {
    x += __int_as_float(__builtin_amdgcn_update_dpp(0, __float_as_int(x), 0x111, 0xf, 0xf, true)); // row_shr:1
    x += __int_as_float(__builtin_amdgcn_update_dpp(0, __float_as_int(x), 0x112, 0xf, 0xf, true)); // row_shr:2
    x += __int_as_float(__builtin_amdgcn_update_dpp(0, __float_as_int(x), 0x114, 0xf, 0xf, true)); // row_shr:4
    x += __int_as_float(__builtin_amdgcn_update_dpp(0, __float_as_int(x), 0x118, 0xf, 0xf, true)); // row_shr:8
    x += __int_as_float(__builtin_amdgcn_update_dpp(0, __float_as_int(x), 0x142, 0xf, 0xf, true)); // row_bcast:15
    x += __int_as_float(__builtin_amdgcn_update_dpp(0, __float_as_int(x), 0x143, 0xf, 0xf, true)); // row_bcast:31
    return x;
}
__device__ __forceinline__ float wave_max_to63(float x) {
    int xi = __float_as_int(x);
    x = fmaxf(x, __int_as_float(__builtin_amdgcn_update_dpp(xi, xi, 0x111, 0xf, 0xf, false))); xi = __float_as_int(x);
    x = fmaxf(x, __int_as_float(__builtin_amdgcn_update_dpp(xi, xi, 0x112, 0xf, 0xf, false))); xi = __float_as_int(x);
    x = fmaxf(x, __int_as_float(__builtin_amdgcn_update_dpp(xi, xi, 0x114, 0xf, 0xf, false))); xi = __float_as_int(x);
    x = fmaxf(x, __int_as_float(__builtin_amdgcn_update_dpp(xi, xi, 0x118, 0xf, 0xf, false))); xi = __float_as_int(x);
    x = fmaxf(x, __int_as_float(__builtin_amdgcn_update_dpp(xi, xi, 0x142, 0xf, 0xf, false))); xi = __float_as_int(x);
    x = fmaxf(x, __int_as_float(__builtin_amdgcn_update_dpp(xi, xi, 0x143, 0xf, 0xf, false)));
    return x;
}
__device__ __forceinline__ float lane63_bcast(float x) {
    return __int_as_float(__builtin_amdgcn_readlane(__float_as_int(x), 63));
}
__device__ __forceinline__ float readlane_f(float x, int i) {
    return __int_as_float(__builtin_amdgcn_readlane(__float_as_int(x), i));
}

// ---------------- CSR build ----------------
__global__ void rank_kernel(const int* __restrict__ dst, int* __restrict__ deg,
                            int* __restrict__ rank) {
    int e = blockIdx.x * blockDim.x + threadIdx.x;
    if (e >= N_EDGES) return;
    rank[e] = atomicAdd(&deg[dst[e]], 1);
}

__global__ void scan_part_kernel(const int* __restrict__ deg, int* __restrict__ bsum) {
    __shared__ int lds[256];
    int b = blockIdx.x, t = threadIdx.x;
    int idx = b * 256 + t;
    lds[t] = (idx < N_NODES) ? deg[idx] : 0;
    __syncthreads();
    for (int off = 128; off >= 1; off >>= 1) {
        if (t < off) lds[t] += lds[t + off];
        __syncthreads();
    }
    if (t == 0) bsum[b] = lds[0];
}

__global__ void scan_top_kernel(const int* __restrict__ bsum, int* __restrict__ boff) {
    __shared__ int lds[256];
    int t = threadIdx.x;
    int v = (t < SCAN_BLOCKS) ? bsum[t] : 0;
    lds[t] = v;
    __syncthreads();
    for (int off = 1; off < 256; off <<= 1) {
        int x = (t >= off) ? lds[t - off] : 0;
        __syncthreads();
        lds[t] += x;
        __syncthreads();
    }
    boff[t] = lds[t] - v;   // exclusive
}

__global__ void scan_final_kernel(const int* __restrict__ deg, const int* __restrict__ boff,
                                  int* __restrict__ row_start) {
    __shared__ int lds[256];
    int b = blockIdx.x, t = threadIdx.x;
    int idx = b * 256 + t;
    int v = (idx < N_NODES) ? deg[idx] : 0;
    lds[t] = v;
    __syncthreads();
    for (int off = 1; off < 256; off <<= 1) {
        int x = (t >= off) ? lds[t - off] : 0;
        __syncthreads();
        lds[t] += x;
        __syncthreads();
    }
    int excl = boff[b] + lds[t] - v;
    if (idx < N_NODES) {
        row_start[idx] = excl;
        if (idx == N_NODES - 1) row_start[N_NODES] = excl + v;
    }
}

// scatter packed 16B entries {src, fp16x2(ea01), fp16x2(ea23), dst}
__global__ void scatter_kernel(const int* __restrict__ src, const int* __restrict__ dst,
                               const int* __restrict__ rank, const int* __restrict__ row_start,
                               const float* __restrict__ edge_attr,
                               int4* __restrict__ csr) {
    int e = blockIdx.x * blockDim.x + threadIdx.x;
    if (e >= N_EDGES) return;
    int d = dst[e];
    int slot = row_start[d] + rank[e];
    float4 ea = ((const float4*)edge_attr)[e];
    __half2 h01 = __floats2half2_rn(ea.x, ea.y);
    __half2 h23 = __floats2half2_rn(ea.z, ea.w);
    int4 ent;
    ent.x = src[e];
    ent.y = *reinterpret_cast<int*>(&h01);
    ent.z = *reinterpret_cast<int*>(&h23);
    ent.w = d;
    csr[slot] = ent;
}

// pack We (both layers) into half2: weh[c*4+k] = {We[k*H+2c], We[k*H+2c+1]}
__global__ void prep_weh_kernel(const float* __restrict__ We0, const float* __restrict__ We1,
                                __half2* __restrict__ weh0, __half2* __restrict__ weh1) {
    int t = threadIdx.x;
    if (t < 32) {
        for (int k = 0; k < 4; ++k)
            weh0[t * 4 + k] = __floats2half2_rn(We0[k * H + 2 * t], We0[k * H + 2 * t + 1]);
    } else if (t < 64) {
        int c = t - 32;
        for (int k = 0; k < 4; ++k)
            weh1[c * 4 + k] = __floats2half2_rn(We1[k * H + 2 * c], We1[k * H + 2 * c + 1]);
    }
}

// ---------------- node projection -> packed fp16 channel pairs ----------------
template <int K>
__global__ void proj_kernel(const float* __restrict__ xin,
                            const float* __restrict__ Wl, const float* __restrict__ bl,
                            const float* __restrict__ Wr, const float* __restrict__ br,
                            __half2* __restrict__ xlh, __half2* __restrict__ xrh) {
    int idx = blockIdx.x * blockDim.x + threadIdx.x;
    if (idx >= N_NODES * 32) return;
    int n = idx >> 5;
    int c = idx & 31;
    const float* xi = xin + n * K;
    float2 bl2 = ((const float2*)bl)[c];
    float2 br2 = ((const float2*)br)[c];
    float al0 = bl2.x, al1 = bl2.y, ar0 = br2.x, ar1 = br2.y;
#pragma unroll
    for (int k = 0; k < K; ++k) {
        float xv = xi[k];
        float2 wl2 = ((const float2*)(Wl + k * H))[c];
        float2 wr2 = ((const float2*)(Wr + k * H))[c];
        al0 += xv * wl2.x; al1 += xv * wl2.y;
        ar0 += xv * wr2.x; ar1 += xv * wr2.y;
    }
    xlh[idx] = __floats2half2_rn(al0, al1);
    xrh[idx] = __floats2half2_rn(ar0, ar1);
}

// ---------------- pass A: per-edge score, lane = edge (no cross-lane ops) ----------------
__global__ __launch_bounds__(256) void score_kernel(
        const int4* __restrict__ csr,
        const __half2* __restrict__ xlh, const __half2* __restrict__ xrh,
        const __half2* __restrict__ weh, const float* __restrict__ att,
        float* __restrict__ score) {
    int e = blockIdx.x * blockDim.x + threadIdx.x;
    if (e >= N_EDGES) return;
    int4 ent = csr[e];
    __half2 ea01 = *reinterpret_cast<__half2*>(&ent.y);
    __half2 ea23 = *reinterpret_cast<__half2*>(&ent.z);
    __half2 e0 = __half2half2(__low2half(ea01));
    __half2 e1 = __half2half2(__high2half(ea01));
    __half2 e2 = __half2half2(__low2half(ea23));
    __half2 e3 = __half2half2(__high2half(ea23));
    const int4* xa = (const int4*)(xlh + ent.x * 32);
    const int4* xb = (const int4*)(xrh + ent.w * 32);
    float acc0 = 0.f, acc1 = 0.f;
#pragma unroll
    for (int k = 0; k < 8; ++k) {
        int4 va = xa[k];
        int4 vb = xb[k];
        const __half2* ha = reinterpret_cast<const __half2*>(&va);
        const __half2* hc = reinterpret_cast<const __half2*>(&vb);
#pragma unroll
        for (int j = 0; j < 4; ++j) {
            int c = k * 4 + j;                     // uniform -> scalar loads
            __half2 v2 = __hadd2(ha[j], hc[j]);
            v2 = __hfma2(e0, weh[c * 4 + 0], v2);
            v2 = __hfma2(e1, weh[c * 4 + 1], v2);
            v2 = __hfma2(e2, weh[c * 4 + 2], v2);
            v2 = __hfma2(e3, weh[c * 4 + 3], v2);
            float2 vf = __half22float2(v2);
            float L0 = fmaxf(vf.x, SLOPE * vf.x);  // leaky_relu (slope<1)
            float L1 = fmaxf(vf.y, SLOPE * vf.y);
            float2 a2 = ((const float2*)att)[c];
            acc0 += L0 * a2.x;
            acc1 += L1 * a2.y;
        }
    }
    score[e] = acc0 + acc1;
}

// ---------------- pass B: aggregation, one wave per node ----------------
// Scores are contiguous per node: exact max + exp + denom are lane-parallel.
// Accumulate: half-wave (lanes 0..31 edge A, 32..63 edge B), channel-pair per lane.
__global__ __launch_bounds__(256) void agg_kernel(
        const int* __restrict__ row_start,
        const int4* __restrict__ csr,
        const float* __restrict__ score,
        const __half2* __restrict__ xlh,
        const float* __restrict__ bias,
        float* __restrict__ out) {
    int wave = (blockIdx.x * blockDim.x + threadIdx.x) >> 6;
    if (wave >= N_NODES) return;
    int lane = threadIdx.x & 63;
    int c = lane & 31;
    int hb = lane >> 5;
    int d = wave;
    int beg = __builtin_amdgcn_readfirstlane(row_start[d]);
    int end = __builtin_amdgcn_readfirstlane(row_start[d + 1]);

    // exact max (lane-parallel over contiguous slab)
    float m = -INFINITY;
    for (int j = beg + lane; j < end; j += 64) m = fmaxf(m, score[j]);
    m = lane63_bcast(wave_max_to63(m));

    float l_lane = 0.f;
    float ax0 = 0.f, ay0 = 0.f, ax1 = 0.f, ay1 = 0.f;

    for (int cbeg = beg; cbeg < end; cbeg += 64) {
        int n = end - cbeg;
        int idx = cbeg + lane;
        float sc = score[min(idx, end - 1)];
        float p = __expf(sc - m);
        p = (lane < n) ? p : 0.f;
        l_lane += p;

        int nn = min(n, 64);
        int j = 0;
        for (; j + 4 <= nn; j += 4) {
            int sA0 = __builtin_amdgcn_readfirstlane(csr[cbeg + j + 0].x);
            int sB0 = __builtin_amdgcn_readfirstlane(csr[cbeg + j + 1].x);
            int sA1 = __builtin_amdgcn_readfirstlane(csr[cbeg + j + 2].x);
            int sB1 = __builtin_amdgcn_readfirstlane(csr[cbeg + j + 3].x);
            float pA0 = readlane_f(p, j + 0), pB0 = readlane_f(p, j + 1);
            float pA1 = readlane_f(p, j + 2), pB1 = readlane_f(p, j + 3);
            int s0 = hb ? sB0 : sA0;
            int s1 = hb ? sB1 : sA1;
            float pv0 = hb ? pB0 : pA0;
            float pv1 = hb ? pB1 : pA1;
            float2 x0 = __half22float2(xlh[s0 * 32 + c]);
            float2 x1 = __half22float2(xlh[s1 * 32 + c]);
            ax0 += pv0 * x0.x; ay0 += pv0 * x0.y;
            ax1 += pv1 * x1.x; ay1 += pv1 * x1.y;
        }
        for (; j + 2 <= nn; j += 2) {
            int sA = __builtin_amdgcn_readfirstlane(csr[cbeg + j + 0].x);
            int sB = __builtin_amdgcn_readfirstlane(csr[cbeg + j + 1].x);
            float pA = readlane_f(p, j + 0), pB = readlane_f(p, j + 1);
            int s = hb ? sB : sA;
            float pv = hb ? pB : pA;
            float2 xf = __half22float2(xlh[s * 32 + c]);
            ax0 += pv * xf.x; ay0 += pv * xf.y;
        }
        if (j < nn) {   // odd leftover: processed by half A only (half B adds 0)
            int sA = __builtin_amdgcn_readfirstlane(csr[cbeg + j].x);
            float pA = readlane_f(p, j);
            float pv = hb ? 0.f : pA;
            float2 xf = __half22float2(xlh[sA * 32 + c]);
            ax0 += pv * xf.x; ay0 += pv * xf.y;
        }
    }

    float l = lane63_bcast(wave_sum_to63(l_lane));
    float accx = ax0 + ax1, accy = ay0 + ay1;
    accx += __shfl_xor(accx, 32, 64);
    accy += __shfl_xor(accy, 32, 64);
    if (hb == 0) {
        float inv = 1.f / (l + 1e-16f);
        float2 b2 = ((const float2*)bias)[c];
        float o0 = accx * inv + b2.x;
        float o1 = accy * inv + b2.y;
        o0 = o0 > 0.f ? o0 : expm1f(o0);
        o1 = o1 > 0.f ? o1 : expm1f(o1);
        ((float2*)out)[d * 32 + c] = float2{o0, o1};
    }
}

// ---------------- pool: one block per graph, binary search on sorted batch ----------------
__global__ __launch_bounds__(256) void pool_mean_kernel(const float* __restrict__ h,
                                                        const int* __restrict__ batch,
                                                        float* __restrict__ gmean) {
    int g = blockIdx.x;
    int lo = 0, hi = N_NODES;
    while (lo < hi) { int mid = (lo + hi) >> 1; if (batch[mid] < g) lo = mid + 1; else hi = mid; }
    int start = lo;
    hi = N_NODES;
    while (lo < hi) { int mid = (lo + hi) >> 1; if (batch[mid] < g + 1) lo = mid + 1; else hi = mid; }
    int end = lo;

    int lane = threadIdx.x & 63;
    int w = threadIdx.x >> 6;
    float s = 0.f;
    for (int n = start + w; n < end; n += 4) s += h[n * H + lane];
    __shared__ float red[4][H];
    red[w][lane] = s;
    __syncthreads();
    if (w == 0) {
        float tot = red[0][lane] + red[1][lane] + red[2][lane] + red[3][lane];
        float cn = (float)(end - start);
        gmean[g * H + lane] = tot / fmaxf(cn, 1.f);
    }
}

// ---------------- head ----------------
__global__ void head_kernel(const float* __restrict__ gmean,
                            const float* __restrict__ fc1w, const float* __restrict__ fc1b,
                            const float* __restrict__ fc2w, const float* __restrict__ fc2b,
                            float* __restrict__ out) {
    __shared__ float g[H];
    __shared__ float f[FC];
    __shared__ float lg[NC];
    int b = blockIdx.x, t = threadIdx.x;
    if (t < H) g[t] = gmean[b * H + t];
    __syncthreads();
    float acc = fc1b[t];
    for (int k = 0; k < H; ++k) acc += g[k] * fc1w[k * FC + t];
    f[t] = fmaxf(acc, 0.f);
    __syncthreads();
    if (t < NC) {
        float a = fc2b[t];
        for (int k = 0; k < FC; ++k) a += f[k] * fc2w[k * NC + t];
        lg[t] = a;
    }
    __syncthreads();
    if (t < NC) {
        float mx = fmaxf(lg[0], lg[1]);
        float lse = mx + logf(expf(lg[0] - mx) + expf(lg[1] - mx));
        out[b * NC + t] = lg[t] - lse;
    }
}

extern "C" void kernel_launch(void* const* d_in, const int* in_sizes, int n_in,
                              void* d_out, int out_size, void* d_ws, size_t ws_size,
                              hipStream_t stream) {
    const float* x         = (const float*)d_in[0];
    const int*   edge_idx  = (const int*)d_in[1];
    const float* edge_attr = (const float*)d_in[2];
    const int*   batch     = (const int*)d_in[3];
    const float* Wl0  = (const float*)d_in[4];
    const float* bl0  = (const float*)d_in[5];
    const float* Wr0  = (const float*)d_in[6];
    const float* br0  = (const float*)d_in[7];
    const float* We0  = (const float*)d_in[8];
    const float* att0 = (const float*)d_in[9];
    const float* bias0= (const float*)d_in[10];
    const float* Wl1  = (const float*)d_in[11];
    const float* bl1  = (const float*)d_in[12];
    const float* Wr1  = (const float*)d_in[13];
    const float* br1  = (const float*)d_in[14];
    const float* We1  = (const float*)d_in[15];
    const float* att1 = (const float*)d_in[16];
    const float* bias1= (const float*)d_in[17];
    const float* fc1w = (const float*)d_in[18];
    const float* fc1b = (const float*)d_in[19];
    const float* fc2w = (const float*)d_in[20];
    const float* fc2b = (const float*)d_in[21];

    const int NH = N_NODES * H;
    __half2* xlh    = (__half2*)d_ws;                 // [N*32]
    __half2* xrh    = xlh + N_NODES * 32;             // [N*32]
    float* C        = (float*)(xrh + N_NODES * 32);   // layer output [N,H] fp32
    int*   deg      = (int*)(C + NH);                 // [N]
    int*   row_start= deg + N_NODES;                  // [N+1]
    int*   bsum     = row_start + N_NODES + 1;        // [256]
    int*   boff     = bsum + 256;                     // [256]
    __half2* weh0   = (__half2*)(boff + 256);         // [128]
    __half2* weh1   = weh0 + 128;                     // [128]
    char*  after    = (char*)(weh1 + 128);
    size_t csr_off  = (((size_t)(after - (char*)d_ws)) + 15) & ~(size_t)15;
    int4*  csr      = (int4*)((char*)d_ws + csr_off); // [E] packed 16B
    float* escore   = (float*)((char*)csr + (size_t)N_EDGES * sizeof(int4)); // [E]
    float* gmean    = escore + N_EDGES;               // [G,H]
    int*   rank     = (int*)(gmean + G_GRAPHS * H);   // [E]

    const int* src = edge_idx;
    const int* dst = edge_idx + N_EDGES;

    const int pairBlocks = (N_NODES * 32 + 255) / 256;
    const int edgeBlocks = (N_EDGES + 255) / 256;
    const int waveBlocks = (N_NODES * 64 + 255) / 256;

    // ---- CSR build ----
    (void)hipMemsetAsync(deg, 0, (size_t)N_NODES * sizeof(int), stream);
    rank_kernel<<<edgeBlocks, 256, 0, stream>>>(dst, deg, rank);
    scan_part_kernel<<<SCAN_BLOCKS, 256, 0, stream>>>(deg, bsum);
    scan_top_kernel<<<1, 256, 0, stream>>>(bsum, boff);
    scan_final_kernel<<<SCAN_BLOCKS, 256, 0, stream>>>(deg, boff, row_start);
    scatter_kernel<<<edgeBlocks, 256, 0, stream>>>(src, dst, rank, row_start, edge_attr, csr);
    prep_weh_kernel<<<1, 64, 0, stream>>>(We0, We1, weh0, weh1);

    // ---- layer 0 ----
    proj_kernel<IN_CH><<<pairBlocks, 256, 0, stream>>>(x, Wl0, bl0, Wr0, br0, xlh, xrh);
    score_kernel<<<edgeBlocks, 256, 0, stream>>>(csr, xlh, xrh, weh0, att0, escore);
    agg_kernel<<<waveBlocks, 256, 0, stream>>>(row_start, csr, escore, xlh, bias0, C);

    // ---- layer 1 ----
    proj_kernel<H><<<pairBlocks, 256, 0, stream>>>(C, Wl1, bl1, Wr1, br1, xlh, xrh);
    score_kernel<<<edgeBlocks, 256, 0, stream>>>(csr, xlh, xrh, weh1, att1, escore);
    agg_kernel<<<waveBlocks, 256, 0, stream>>>(row_start, csr, escore, xlh, bias1, C);

    // ---- pool + head ----
    pool_mean_kernel<<<G_GRAPHS, 256, 0, stream>>>(C, batch, gmean);
    head_kernel<<<G_GRAPHS, FC, 0, stream>>>(gmean, fc1w, fc1b, fc2w, fc2b, (float*)d_out);
}

// Round 11
// 486.573 us; speedup vs baseline: 1.2143x; 1.1747x over previous
//
#include <hip/hip_runtime.h>
#include <hip/hip_fp16.h>

#define N_NODES 50000
#define N_EDGES 1600000
#define H 64
#define IN_CH 7
#define EDIM 4
#define G_GRAPHS 256
#define FC 128
#define NC 2
#define SLOPE 0.2f
#define SCAN_BLOCKS ((N_NODES + 255) / 256)   // 196

typedef _Float16 h2v __attribute__((ext_vector_type(2)));

__device__ __forceinline__ float fdot2f(h2v a, h2v b, float c) {
#if defined(__has_builtin) && __has_builtin(__builtin_amdgcn_fdot2)
    return __builtin_amdgcn_fdot2(a, b, c, false);
#else
    return c + (float)a[0] * (float)b[0] + (float)a[1] * (float)b[1];
#endif
}

// ---------------- DPP wave-64 reductions ----------------
__device__ __forceinline__ float wave_sum_to63(float x) {
    x += __int_as_float(__builtin_amdgcn_update_dpp(0, __float_as_int(x), 0x111, 0xf, 0xf, true)); // row_shr:1
    x += __int_as_float(__builtin_amdgcn_update_dpp(0, __float_as_int(x), 0x112, 0xf, 0xf, true)); // row_shr:2
    x += __int_as_float(__builtin_amdgcn_update_dpp(0, __float_as_int(x), 0x114, 0xf, 0xf, true)); // row_shr:4
    x += __int_as_float(__builtin_amdgcn_update_dpp(0, __float_as_int(x), 0x118, 0xf, 0xf, true)); // row_shr:8
    x += __int_as_float(__builtin_amdgcn_update_dpp(0, __float_as_int(x), 0x142, 0xf, 0xf, true)); // row_bcast:15
    x += __int_as_float(__builtin_amdgcn_update_dpp(0, __float_as_int(x), 0x143, 0xf, 0xf, true)); // row_bcast:31
    return x;
}
__device__ __forceinline__ float wave_max_to63(float x) {
    int xi = __float_as_int(x);
    x = fmaxf(x, __int_as_float(__builtin_amdgcn_update_dpp(xi, xi, 0x111, 0xf, 0xf, false))); xi = __float_as_int(x);
    x = fmaxf(x, __int_as_float(__builtin_amdgcn_update_dpp(xi, xi, 0x112, 0xf, 0xf, false))); xi = __float_as_int(x);
    x = fmaxf(x, __int_as_float(__builtin_amdgcn_update_dpp(xi, xi, 0x114, 0xf, 0xf, false))); xi = __float_as_int(x);
    x = fmaxf(x, __int_as_float(__builtin_amdgcn_update_dpp(xi, xi, 0x118, 0xf, 0xf, false))); xi = __float_as_int(x);
    x = fmaxf(x, __int_as_float(__builtin_amdgcn_update_dpp(xi, xi, 0x142, 0xf, 0xf, false))); xi = __float_as_int(x);
    x = fmaxf(x, __int_as_float(__builtin_amdgcn_update_dpp(xi, xi, 0x143, 0xf, 0xf, false)));
    return x;
}
__device__ __forceinline__ float lane63_bcast(float x) {
    return __int_as_float(__builtin_amdgcn_readlane(__float_as_int(x), 63));
}
__device__ __forceinline__ float readlane_f(float x, int i) {
    return __int_as_float(__builtin_amdgcn_readlane(__float_as_int(x), i));
}

// ---------------- CSR build ----------------
__global__ void rank_kernel(const int* __restrict__ dst, int* __restrict__ deg,
                            int* __restrict__ rank) {
    int e = blockIdx.x * blockDim.x + threadIdx.x;
    if (e >= N_EDGES) return;
    rank[e] = atomicAdd(&deg[dst[e]], 1);
}

__global__ void scan_part_kernel(const int* __restrict__ deg, int* __restrict__ bsum) {
    __shared__ int lds[256];
    int b = blockIdx.x, t = threadIdx.x;
    int idx = b * 256 + t;
    lds[t] = (idx < N_NODES) ? deg[idx] : 0;
    __syncthreads();
    for (int off = 128; off >= 1; off >>= 1) {
        if (t < off) lds[t] += lds[t + off];
        __syncthreads();
    }
    if (t == 0) bsum[b] = lds[0];
}

__global__ void scan_top_kernel(const int* __restrict__ bsum, int* __restrict__ boff) {
    __shared__ int lds[256];
    int t = threadIdx.x;
    int v = (t < SCAN_BLOCKS) ? bsum[t] : 0;
    lds[t] = v;
    __syncthreads();
    for (int off = 1; off < 256; off <<= 1) {
        int x = (t >= off) ? lds[t - off] : 0;
        __syncthreads();
        lds[t] += x;
        __syncthreads();
    }
    boff[t] = lds[t] - v;   // exclusive
}

__global__ void scan_final_kernel(const int* __restrict__ deg, const int* __restrict__ boff,
                                  int* __restrict__ row_start) {
    __shared__ int lds[256];
    int b = blockIdx.x, t = threadIdx.x;
    int idx = b * 256 + t;
    int v = (idx < N_NODES) ? deg[idx] : 0;
    lds[t] = v;
    __syncthreads();
    for (int off = 1; off < 256; off <<= 1) {
        int x = (t >= off) ? lds[t - off] : 0;
        __syncthreads();
        lds[t] += x;
        __syncthreads();
    }
    int excl = boff[b] + lds[t] - v;
    if (idx < N_NODES) {
        row_start[idx] = excl;
        if (idx == N_NODES - 1) row_start[N_NODES] = excl + v;
    }
}

// scatter packed 16B entries {src, fp16x2(ea01), fp16x2(ea23), dst}
__global__ void scatter_kernel(const int* __restrict__ src, const int* __restrict__ dst,
                               const int* __restrict__ rank, const int* __restrict__ row_start,
                               const float* __restrict__ edge_attr,
                               int4* __restrict__ csr) {
    int e = blockIdx.x * blockDim.x + threadIdx.x;
    if (e >= N_EDGES) return;
    int d = dst[e];
    int slot = row_start[d] + rank[e];
    float4 ea = ((const float4*)edge_attr)[e];
    __half2 h01 = __floats2half2_rn(ea.x, ea.y);
    __half2 h23 = __floats2half2_rn(ea.z, ea.w);
    int4 ent;
    ent.x = src[e];
    ent.y = *reinterpret_cast<int*>(&h01);
    ent.z = *reinterpret_cast<int*>(&h23);
    ent.w = d;
    csr[slot] = ent;
}

// pack We (both layers) into half2: weh[c*4+k] = {We[k*H+2c], We[k*H+2c+1]}
__global__ void prep_weh_kernel(const float* __restrict__ We0, const float* __restrict__ We1,
                                __half2* __restrict__ weh0, __half2* __restrict__ weh1) {
    int t = threadIdx.x;
    if (t < 32) {
        for (int k = 0; k < 4; ++k)
            weh0[t * 4 + k] = __floats2half2_rn(We0[k * H + 2 * t], We0[k * H + 2 * t + 1]);
    } else if (t < 64) {
        int c = t - 32;
        for (int k = 0; k < 4; ++k)
            weh1[c * 4 + k] = __floats2half2_rn(We1[k * H + 2 * c], We1[k * H + 2 * c + 1]);
    }
}

// transposed+paired layer-1 proj weights: wt[ch*32+kk] = {W[2kk][c], W[2kk+1][c]}
// ch 0..63 = Wl1 cols, ch 64..127 = Wr1 cols. bb[ch] = bias.
__global__ void prep_wt_kernel(const float* __restrict__ Wl1, const float* __restrict__ bl1,
                               const float* __restrict__ Wr1, const float* __restrict__ br1,
                               __half2* __restrict__ wt, float* __restrict__ bb) {
    int ch = threadIdx.x;
    if (ch >= 128) return;
    const float* W = (ch < 64) ? Wl1 : Wr1;
    int c = ch & 63;
    for (int kk = 0; kk < 32; ++kk)
        wt[ch * 32 + kk] = __floats2half2_rn(W[(2 * kk) * H + c], W[(2 * kk + 1) * H + c]);
    bb[ch] = (ch < 64) ? bl1[c] : br1[c];
}

// ---------------- layer-0 projection (K=7) -> packed fp16 channel pairs ----------------
__global__ void proj0_kernel(const float* __restrict__ xin,
                             const float* __restrict__ Wl, const float* __restrict__ bl,
                             const float* __restrict__ Wr, const float* __restrict__ br,
                             __half2* __restrict__ xlh, __half2* __restrict__ xrh) {
    int idx = blockIdx.x * blockDim.x + threadIdx.x;
    if (idx >= N_NODES * 32) return;
    int n = idx >> 5;
    int c = idx & 31;
    const float* xi = xin + n * IN_CH;
    float2 bl2 = ((const float2*)bl)[c];
    float2 br2 = ((const float2*)br)[c];
    float al0 = bl2.x, al1 = bl2.y, ar0 = br2.x, ar1 = br2.y;
#pragma unroll
    for (int k = 0; k < IN_CH; ++k) {
        float xv = xi[k];
        float2 wl2 = ((const float2*)(Wl + k * H))[c];
        float2 wr2 = ((const float2*)(Wr + k * H))[c];
        al0 += xv * wl2.x; al1 += xv * wl2.y;
        ar0 += xv * wr2.x; ar1 += xv * wr2.y;
    }
    xlh[idx] = __floats2half2_rn(al0, al1);
    xrh[idx] = __floats2half2_rn(ar0, ar1);
}

// ---------------- layer-1 projection: lane = node, scalar weights ----------------
// Wave w of block handles 64 nodes x 32 output channels (of 128 combined xl|xr).
// Weights via wave-uniform addresses (s_load); dot via v_dot2_f32_f16 (fp32 acc).
__global__ __launch_bounds__(256) void proj1_kernel(
        const float* __restrict__ xin,        // C fp32 [N,64]
        const __half2* __restrict__ wt,       // [128][32] half2
        const float* __restrict__ bb,         // [128]
        __half2* __restrict__ xlh, __half2* __restrict__ xrh) {
    int g = __builtin_amdgcn_readfirstlane((int)(threadIdx.x >> 6));  // chan group 0..3
    int lane = threadIdx.x & 63;
    int node = blockIdx.x * 64 + lane;
    if (node >= N_NODES) return;

    // load x row fp32 -> 32 half2 VGPRs
    h2v xrow[32];
    const float4* xp = (const float4*)(xin + node * 64);
#pragma unroll
    for (int q = 0; q < 16; ++q) {
        float4 v = xp[q];
        __half2 a = __floats2half2_rn(v.x, v.y);
        __half2 b = __floats2half2_rn(v.z, v.w);
        xrow[2 * q]     = *reinterpret_cast<h2v*>(&a);
        xrow[2 * q + 1] = *reinterpret_cast<h2v*>(&b);
    }

    __half2* outp = (g < 2) ? xlh : xrh;
    int chbase = g * 32;            // combined channel base
    int localbase = (g & 1) * 16;   // half2-pair offset within node's 32 pairs

#pragma unroll
    for (int cp = 0; cp < 16; ++cp) {
        int ch0 = chbase + 2 * cp;
        const h2v* w0 = (const h2v*)(wt + ch0 * 32);
        const h2v* w1 = (const h2v*)(wt + (ch0 + 1) * 32);
        float a0 = bb[ch0], a1 = bb[ch0 + 1];
#pragma unroll
        for (int kk = 0; kk < 32; ++kk) {
            a0 = fdot2f(xrow[kk], w0[kk], a0);
            a1 = fdot2f(xrow[kk], w1[kk], a1);
        }
        outp[node * 32 + localbase + cp] = __floats2half2_rn(a0, a1);
    }
}

// ---------------- pass A: per-edge score, lane = edge (no cross-lane ops) ----------------
__global__ __launch_bounds__(256) void score_kernel(
        const int4* __restrict__ csr,
        const __half2* __restrict__ xlh, const __half2* __restrict__ xrh,
        const __half2* __restrict__ weh, const float* __restrict__ att,
        float* __restrict__ score) {
    int e = blockIdx.x * blockDim.x + threadIdx.x;
    if (e >= N_EDGES) return;
    int4 ent = csr[e];
    __half2 ea01 = *reinterpret_cast<__half2*>(&ent.y);
    __half2 ea23 = *reinterpret_cast<__half2*>(&ent.z);
    __half2 e0 = __half2half2(__low2half(ea01));
    __half2 e1 = __half2half2(__high2half(ea01));
    __half2 e2 = __half2half2(__low2half(ea23));
    __half2 e3 = __half2half2(__high2half(ea23));
    const int4* xa = (const int4*)(xlh + ent.x * 32);
    const int4* xb = (const int4*)(xrh + ent.w * 32);
    float acc0 = 0.f, acc1 = 0.f;
#pragma unroll
    for (int k = 0; k < 8; ++k) {
        int4 va = xa[k];
        int4 vb = xb[k];
        const __half2* ha = reinterpret_cast<const __half2*>(&va);
        const __half2* hc = reinterpret_cast<const __half2*>(&vb);
#pragma unroll
        for (int j = 0; j < 4; ++j) {
            int c = k * 4 + j;                     // uniform -> scalar loads
            __half2 v2 = __hadd2(ha[j], hc[j]);
            v2 = __hfma2(e0, weh[c * 4 + 0], v2);
            v2 = __hfma2(e1, weh[c * 4 + 1], v2);
            v2 = __hfma2(e2, weh[c * 4 + 2], v2);
            v2 = __hfma2(e3, weh[c * 4 + 3], v2);
            float2 vf = __half22float2(v2);
            float L0 = fmaxf(vf.x, SLOPE * vf.x);  // leaky_relu (slope<1)
            float L1 = fmaxf(vf.y, SLOPE * vf.y);
            float2 a2 = ((const float2*)att)[c];
            acc0 += L0 * a2.x;
            acc1 += L1 * a2.y;
        }
    }
    score[e] = acc0 + acc1;
}

// ---------------- pass B: aggregation, one wave per node ----------------
__global__ __launch_bounds__(256) void agg_kernel(
        const int* __restrict__ row_start,
        const int4* __restrict__ csr,
        const float* __restrict__ score,
        const __half2* __restrict__ xlh,
        const float* __restrict__ bias,
        float* __restrict__ out) {
    int wave = (blockIdx.x * blockDim.x + threadIdx.x) >> 6;
    if (wave >= N_NODES) return;
    int lane = threadIdx.x & 63;
    int c = lane & 31;
    int hb = lane >> 5;
    int d = wave;
    int beg = __builtin_amdgcn_readfirstlane(row_start[d]);
    int end = __builtin_amdgcn_readfirstlane(row_start[d + 1]);

    // exact max (lane-parallel over contiguous slab)
    float m = -INFINITY;
    for (int j = beg + lane; j < end; j += 64) m = fmaxf(m, score[j]);
    m = lane63_bcast(wave_max_to63(m));

    float l_lane = 0.f;
    float ax0 = 0.f, ay0 = 0.f, ax1 = 0.f, ay1 = 0.f;

    for (int cbeg = beg; cbeg < end; cbeg += 64) {
        int n = end - cbeg;
        int idx = cbeg + lane;
        float sc = score[min(idx, end - 1)];
        float p = __expf(sc - m);
        p = (lane < n) ? p : 0.f;
        l_lane += p;

        int nn = min(n, 64);
        int j = 0;
        for (; j + 4 <= nn; j += 4) {
            int sA0 = __builtin_amdgcn_readfirstlane(csr[cbeg + j + 0].x);
            int sB0 = __builtin_amdgcn_readfirstlane(csr[cbeg + j + 1].x);
            int sA1 = __builtin_amdgcn_readfirstlane(csr[cbeg + j + 2].x);
            int sB1 = __builtin_amdgcn_readfirstlane(csr[cbeg + j + 3].x);
            float pA0 = readlane_f(p, j + 0), pB0 = readlane_f(p, j + 1);
            float pA1 = readlane_f(p, j + 2), pB1 = readlane_f(p, j + 3);
            int s0 = hb ? sB0 : sA0;
            int s1 = hb ? sB1 : sA1;
            float pv0 = hb ? pB0 : pA0;
            float pv1 = hb ? pB1 : pA1;
            float2 x0 = __half22float2(xlh[s0 * 32 + c]);
            float2 x1 = __half22float2(xlh[s1 * 32 + c]);
            ax0 += pv0 * x0.x; ay0 += pv0 * x0.y;
            ax1 += pv1 * x1.x; ay1 += pv1 * x1.y;
        }
        for (; j + 2 <= nn; j += 2) {
            int sA = __builtin_amdgcn_readfirstlane(csr[cbeg + j + 0].x);
            int sB = __builtin_amdgcn_readfirstlane(csr[cbeg + j + 1].x);
            float pA = readlane_f(p, j + 0), pB = readlane_f(p, j + 1);
            int s = hb ? sB : sA;
            float pv = hb ? pB : pA;
            float2 xf = __half22float2(xlh[s * 32 + c]);
            ax0 += pv * xf.x; ay0 += pv * xf.y;
        }
        if (j < nn) {   // odd leftover: half A only (half B adds 0)
            int sA = __builtin_amdgcn_readfirstlane(csr[cbeg + j].x);
            float pA = readlane_f(p, j);
            float pv = hb ? 0.f : pA;
            float2 xf = __half22float2(xlh[sA * 32 + c]);
            ax0 += pv * xf.x; ay0 += pv * xf.y;
        }
    }

    float l = lane63_bcast(wave_sum_to63(l_lane));
    float accx = ax0 + ax1, accy = ay0 + ay1;
    accx += __shfl_xor(accx, 32, 64);
    accy += __shfl_xor(accy, 32, 64);
    if (hb == 0) {
        float inv = 1.f / (l + 1e-16f);
        float2 b2 = ((const float2*)bias)[c];
        float o0 = accx * inv + b2.x;
        float o1 = accy * inv + b2.y;
        o0 = o0 > 0.f ? o0 : expm1f(o0);
        o1 = o1 > 0.f ? o1 : expm1f(o1);
        ((float2*)out)[d * 32 + c] = float2{o0, o1};
    }
}

// ---------------- pool: one block per graph, binary search on sorted batch ----------------
__global__ __launch_bounds__(256) void pool_mean_kernel(const float* __restrict__ h,
                                                        const int* __restrict__ batch,
                                                        float* __restrict__ gmean) {
    int g = blockIdx.x;
    int lo = 0, hi = N_NODES;
    while (lo < hi) { int mid = (lo + hi) >> 1; if (batch[mid] < g) lo = mid + 1; else hi = mid; }
    int start = lo;
    hi = N_NODES;
    while (lo < hi) { int mid = (lo + hi) >> 1; if (batch[mid] < g + 1) lo = mid + 1; else hi = mid; }
    int end = lo;

    int lane = threadIdx.x & 63;
    int w = threadIdx.x >> 6;
    float s = 0.f;
    for (int n = start + w; n < end; n += 4) s += h[n * H + lane];
    __shared__ float red[4][H];
    red[w][lane] = s;
    __syncthreads();
    if (w == 0) {
        float tot = red[0][lane] + red[1][lane] + red[2][lane] + red[3][lane];
        float cn = (float)(end - start);
        gmean[g * H + lane] = tot / fmaxf(cn, 1.f);
    }
}

// ---------------- head ----------------
__global__ void head_kernel(const float* __restrict__ gmean,
                            const float* __restrict__ fc1w, const float* __restrict__ fc1b,
                            const float* __restrict__ fc2w, const float* __restrict__ fc2b,
                            float* __restrict__ out) {
    __shared__ float g[H];
    __shared__ float f[FC];
    __shared__ float lg[NC];
    int b = blockIdx.x, t = threadIdx.x;
    if (t < H) g[t] = gmean[b * H + t];
    __syncthreads();
    float acc = fc1b[t];
    for (int k = 0; k < H; ++k) acc += g[k] * fc1w[k * FC + t];
    f[t] = fmaxf(acc, 0.f);
    __syncthreads();
    if (t < NC) {
        float a = fc2b[t];
        for (int k = 0; k < FC; ++k) a += f[k] * fc2w[k * NC + t];
        lg[t] = a;
    }
    __syncthreads();
    if (t < NC) {
        float mx = fmaxf(lg[0], lg[1]);
        float lse = mx + logf(expf(lg[0] - mx) + expf(lg[1] - mx));
        out[b * NC + t] = lg[t] - lse;
    }
}

extern "C" void kernel_launch(void* const* d_in, const int* in_sizes, int n_in,
                              void* d_out, int out_size, void* d_ws, size_t ws_size,
                              hipStream_t stream) {
    const float* x         = (const float*)d_in[0];
    const int*   edge_idx  = (const int*)d_in[1];
    const float* edge_attr = (const float*)d_in[2];
    const int*   batch     = (const int*)d_in[3];
    const float* Wl0  = (const float*)d_in[4];
    const float* bl0  = (const float*)d_in[5];
    const float* Wr0  = (const float*)d_in[6];
    const float* br0  = (const float*)d_in[7];
    const float* We0  = (const float*)d_in[8];
    const float* att0 = (const float*)d_in[9];
    const float* bias0= (const float*)d_in[10];
    const float* Wl1  = (const float*)d_in[11];
    const float* bl1  = (const float*)d_in[12];
    const float* Wr1  = (const float*)d_in[13];
    const float* br1  = (const float*)d_in[14];
    const float* We1  = (const float*)d_in[15];
    const float* att1 = (const float*)d_in[16];
    const float* bias1= (const float*)d_in[17];
    const float* fc1w = (const float*)d_in[18];
    const float* fc1b = (const float*)d_in[19];
    const float* fc2w = (const float*)d_in[20];
    const float* fc2b = (const float*)d_in[21];

    const int NH = N_NODES * H;
    __half2* xlh    = (__half2*)d_ws;                 // [N*32]
    __half2* xrh    = xlh + N_NODES * 32;             // [N*32]
    float* C        = (float*)(xrh + N_NODES * 32);   // layer output [N,H] fp32
    int*   deg      = (int*)(C + NH);                 // [N]
    int*   row_start= deg + N_NODES;                  // [N+1]
    int*   bsum     = row_start + N_NODES + 1;        // [256]
    int*   boff     = bsum + 256;                     // [256]
    __half2* weh0   = (__half2*)(boff + 256);         // [128]
    __half2* weh1   = weh0 + 128;                     // [128]
    __half2* wt1    = weh1 + 128;                     // [128*32]
    float* bb1      = (float*)(wt1 + 128 * 32);       // [128]
    char*  after    = (char*)(bb1 + 128);
    size_t csr_off  = (((size_t)(after - (char*)d_ws)) + 15) & ~(size_t)15;
    int4*  csr      = (int4*)((char*)d_ws + csr_off); // [E] packed 16B
    float* escore   = (float*)((char*)csr + (size_t)N_EDGES * sizeof(int4)); // [E]
    float* gmean    = escore + N_EDGES;               // [G,H]
    int*   rank     = (int*)(gmean + G_GRAPHS * H);   // [E]

    const int* src = edge_idx;
    const int* dst = edge_idx + N_EDGES;

    const int pairBlocks = (N_NODES * 32 + 255) / 256;
    const int edgeBlocks = (N_EDGES + 255) / 256;
    const int waveBlocks = (N_NODES * 64 + 255) / 256;
    const int p1Blocks   = (N_NODES + 63) / 64;       // proj1: 64 nodes/block

    // ---- CSR build ----
    (void)hipMemsetAsync(deg, 0, (size_t)N_NODES * sizeof(int), stream);
    rank_kernel<<<edgeBlocks, 256, 0, stream>>>(dst, deg, rank);
    scan_part_kernel<<<SCAN_BLOCKS, 256, 0, stream>>>(deg, bsum);
    scan_top_kernel<<<1, 256, 0, stream>>>(bsum, boff);
    scan_final_kernel<<<SCAN_BLOCKS, 256, 0, stream>>>(deg, boff, row_start);
    scatter_kernel<<<edgeBlocks, 256, 0, stream>>>(src, dst, rank, row_start, edge_attr, csr);
    prep_weh_kernel<<<1, 64, 0, stream>>>(We0, We1, weh0, weh1);
    prep_wt_kernel<<<1, 128, 0, stream>>>(Wl1, bl1, Wr1, br1, wt1, bb1);

    // ---- layer 0 ----
    proj0_kernel<<<pairBlocks, 256, 0, stream>>>(x, Wl0, bl0, Wr0, br0, xlh, xrh);
    score_kernel<<<edgeBlocks, 256, 0, stream>>>(csr, xlh, xrh, weh0, att0, escore);
    agg_kernel<<<waveBlocks, 256, 0, stream>>>(row_start, csr, escore, xlh, bias0, C);

    // ---- layer 1 ----
    proj1_kernel<<<p1Blocks, 256, 0, stream>>>(C, wt1, bb1, xlh, xrh);
    score_kernel<<<edgeBlocks, 256, 0, stream>>>(csr, xlh, xrh, weh1, att1, escore);
    agg_kernel<<<waveBlocks, 256, 0, stream>>>(row_start, csr, escore, xlh, bias1, C);

    // ---- pool + head ----
    pool_mean_kernel<<<G_GRAPHS, 256, 0, stream>>>(C, batch, gmean);
    head_kernel<<<G_GRAPHS, FC, 0, stream>>>(gmean, fc1w, fc1b, fc2w, fc2b, (float*)d_out);
}